// Round 1
// baseline (27283.295 us; speedup 1.0000x reference)
//
#include <hip/hip_runtime.h>
#include <cstdint>

#define NB 128      // batch
#define DH 512      // D == H
#define ROWS 528    // DH + 16 pad rows (prefetch overrun)

// ---- workspace layout (float offsets) ----
#define OFF_M   0u          // [128 chunks][512 k][16 c]  folded [Ar|Az|Ah|Wo]
#define OFF_M1  1048576u    // [128][512][16]             step-1 [Wr|Wz|Wh|0]
#define OFF_UH  2097152u    // [64 chunks][512 k][8 c]    Uh
#define OFF_H   2359296u    // [528][128]  h (transposed, padded)
#define OFF_RH  2426880u    // [528][128]  r*h
#define OFF_XT  2494464u    // [528][128]  inputs^T
#define OFF_GZ  2562048u    // [512][128]  z gate (activated)
#define OFF_GH  2627584u    // [512][128]  pre-h (x-part + bias)
#define OFF_CV  2693120u    // [2048] folded biases
#define OFF_C1  2695168u    // [2048] step-1 biases
#define OFF_BAR 2697216u    // 1024 uint32 barrier state

__device__ __forceinline__ float sigm(float x) { return 1.f / (1.f + __expf(-x)); }
__device__ __forceinline__ float tanh_fast(float x) {
  float e = __expf(2.f * fminf(x, 40.f));
  return (e - 1.f) / (e + 1.f);
}

// ======================= precompute kernel =======================
__global__ __launch_bounds__(256) void gru_pre(
    const float* __restrict__ inputs,
    const float* __restrict__ Wz, const float* __restrict__ Wr, const float* __restrict__ Wh,
    const float* __restrict__ Uz, const float* __restrict__ Ur, const float* __restrict__ Uh,
    const float* __restrict__ bz, const float* __restrict__ br, const float* __restrict__ bh,
    const float* __restrict__ Wo, const float* __restrict__ bo,
    float* __restrict__ ws)
{
  __shared__ float sh[8960];            // 35 KB scratch, reused per task
  const int bid = blockIdx.x, t = threadIdx.x;
  float* Mw  = ws + OFF_M;
  float* M1w = ws + OFF_M1;
  float* Uhw = ws + OFF_UH;
  float* hw  = ws + OFF_H;
  float* rhw = ws + OFF_RH;
  float* xT  = ws + OFF_XT;
  float* cv  = ws + OFF_CV;
  float* c1  = ws + OFF_C1;
  uint32_t* bar = (uint32_t*)(ws + OFF_BAR);

  if (bid < 256) {
    // ---- build M = [Wo@Wr+Ur | Wo@Wz+Uz | Wo@Wh | Wo] ----
    const int kh = bid >> 7, cch = bid & 127;
    const int reg = cch >> 5;
    const int k0 = kh * 256, c0 = cch * 16;
    if (reg == 3) {
      const int cc0 = c0 - 1536;
      for (int i = 0; i < 16; ++i) {
        int idx = t + i * 256;
        int kk = k0 + (idx >> 4), ci = idx & 15;
        Mw[(cch * 512 + kk) * 16 + ci] = Wo[kk * 512 + cc0 + ci];
      }
    } else {
      const float* Ws = (reg == 0) ? Wr : (reg == 1) ? Wz : Wh;
      const float* Us = (reg == 0) ? Ur : (reg == 1) ? Uz : nullptr;
      const int cc0 = c0 - reg * 512;
      const int kl = t;                 // 256 threads <-> 256 local k rows
      const int k = k0 + kl;
      float acc[16];
      #pragma unroll
      for (int c = 0; c < 16; ++c) acc[c] = 0.f;
      for (int jt = 0; jt < 16; ++jt) {          // 32-wide j tiles of Wo
        __syncthreads();
        for (int i = 0; i < 32; ++i) {
          int idx = t + i * 256;                 // 8192 = 256k x 32j
          int kk = idx >> 5, jj = idx & 31;
          sh[kk * 35 + jj] = Wo[(k0 + kk) * 512 + jt * 32 + jj];
        }
        __syncthreads();
        for (int j = 0; j < 32; ++j) {
          float wv = sh[kl * 35 + j];
          const float* wrow = Ws + (jt * 32 + j) * 512 + cc0;
          #pragma unroll
          for (int c = 0; c < 16; ++c) acc[c] = fmaf(wv, wrow[c], acc[c]);
        }
      }
      #pragma unroll
      for (int c = 0; c < 16; ++c) {
        float v = acc[c];
        if (Us) v += Us[k * 512 + cc0 + c];
        Mw[(cch * 512 + k) * 16 + c] = v;
      }
    }
  }
  else if (bid < 264) {
    // ---- cvec = bo @ W* + b*   (region 3: just bo) ----
    const int q = bid - 256;
    const int r2 = q >> 1;
    const float* Ws = (r2 == 0) ? Wr : (r2 == 1) ? Wz : (r2 == 2) ? Wh : nullptr;
    const float* bs = (r2 == 0) ? br : (r2 == 1) ? bz : (r2 == 2) ? bh : nullptr;
    for (int round = 0; round < 8; ++round) {
      int col32 = t >> 3, strip = t & 7;
      int c = q * 256 + round * 32 + col32;
      int cc = c & 511;
      float p = 0.f;
      if (r2 < 3) {
        for (int j = strip * 64; j < strip * 64 + 64; ++j)
          p = fmaf(bo[j], Ws[j * 512 + cc], p);
      }
      sh[col32 * 8 + strip] = p;
      __syncthreads();
      if (t < 32) {
        float v = 0.f;
        #pragma unroll
        for (int st = 0; st < 8; ++st) v += sh[t * 8 + st];
        int c2 = q * 256 + round * 32 + t;
        int cc2 = c2 & 511;
        cv[c2] = (r2 < 3) ? (v + bs[cc2]) : bo[cc2];
      }
      __syncthreads();
    }
  }
  else if (bid < 288) {
    // ---- M1 = [Wr|Wz|Wh] copy (chunks 0..95) ----
    const int q = bid - 264;
    for (int cq = 0; cq < 4; ++cq) {
      int ch = q * 4 + cq;
      int r3 = ch >> 5;
      const float* Ws = (r3 == 0) ? Wr : (r3 == 1) ? Wz : Wh;
      int cc0 = (ch & 31) * 16;
      for (int i = 0; i < 32; ++i) {
        int idx = t + i * 256;
        int kk = idx >> 4, ci = idx & 15;
        M1w[(ch * 512 + kk) * 16 + ci] = Ws[kk * 512 + cc0 + ci];
      }
    }
  }
  else if (bid < 296) {
    // ---- M1 Wo-part zero (chunks 96..127) ----
    const int q = bid - 288;
    for (int cq = 0; cq < 4; ++cq) {
      int ch = 96 + q * 4 + cq;
      for (int i = 0; i < 32; ++i) {
        int idx = t + i * 256;
        M1w[ch * 8192 + idx] = 0.f;
      }
    }
  }
  else if (bid < 312) {
    // ---- Uh reshape to [chunk][k][8] ----
    const int q = bid - 296;
    for (int cq = 0; cq < 4; ++cq) {
      int ch = q * 4 + cq;
      for (int i = 0; i < 16; ++i) {
        int idx = t + i * 256;
        int kk = idx >> 3, ci = idx & 7;
        Uhw[(ch * 512 + kk) * 8 + ci] = Uh[kk * 512 + ch * 8 + ci];
      }
    }
  }
  else if (bid < 316) {
    // ---- xT = inputs^T (64x64 LDS tiles) ----
    const int q = bid - 312;
    for (int ti = q * 4; ti < q * 4 + 4; ++ti) {
      int bt = ti >> 3, dt = ti & 7;
      __syncthreads();
      for (int i = 0; i < 16; ++i) {
        int idx = t + i * 256;
        int r = idx >> 6, c = idx & 63;
        sh[r * 65 + c] = inputs[(bt * 64 + r) * 512 + dt * 64 + c];
      }
      __syncthreads();
      for (int i = 0; i < 16; ++i) {
        int idx = t + i * 256;
        int r = idx >> 6, c = idx & 63;
        xT[(dt * 64 + r) * 128 + bt * 64 + c] = sh[c * 65 + r];
      }
    }
    if (q == 0) {
      for (int idx = t; idx < 16 * 128; idx += 256) xT[512 * 128 + idx] = 0.f;
    }
  }
  else if (bid == 316) {
    for (int idx = t; idx < ROWS * 128; idx += 256) hw[idx] = 0.f;     // h0 = 0 (+pads)
  }
  else if (bid == 317) {
    for (int idx = t; idx < 16 * 128; idx += 256) rhw[512 * 128 + idx] = 0.f;  // rh pads
  }
  else if (bid == 318) {
    for (int idx = t; idx < 2048; idx += 256)
      c1[idx] = (idx < 512) ? br[idx] : (idx < 1024) ? bz[idx - 512]
              : (idx < 1536) ? bh[idx - 1024] : 0.f;
    for (int idx = t; idx < 1024; idx += 256) bar[idx] = 0u;
  }
}

// ======================= global barrier =======================
__device__ __forceinline__ void gbar(uint32_t* bar, int xcd, uint32_t ph) {
  __syncthreads();
  if (threadIdx.x == 0) {
    __threadfence();  // release our writes to device scope
    uint32_t o = __hip_atomic_fetch_add(&bar[xcd * 32], 1u, __ATOMIC_RELAXED, __HIP_MEMORY_SCOPE_AGENT);
    if (o == ph * 32u + 31u) {                    // last of this xcd-group
      uint32_t g = __hip_atomic_fetch_add(&bar[256], 1u, __ATOMIC_RELAXED, __HIP_MEMORY_SCOPE_AGENT);
      if (g == ph * 8u + 7u) {                    // last globally
        #pragma unroll
        for (int x = 0; x < 8; ++x)
          __hip_atomic_store(&bar[512 + x * 32], ph + 1u, __ATOMIC_RELAXED, __HIP_MEMORY_SCOPE_AGENT);
      }
    }
    int guard = 0;
    while (__hip_atomic_load(&bar[512 + xcd * 32], __ATOMIC_RELAXED, __HIP_MEMORY_SCOPE_AGENT) < ph + 1u) {
      __builtin_amdgcn_s_sleep(1);
      if (++guard > (1 << 24)) break;             // anti-hang safety
    }
    __threadfence();  // acquire: invalidate caches before reading others' data
  }
  __syncthreads();
}

// ======================= persistent main kernel =======================
__global__ __launch_bounds__(256, 1) void gru_main(
    const float* __restrict__ inputs,
    const float* __restrict__ Mw, const float* __restrict__ M1w,
    const float* __restrict__ Uhw,
    const float* __restrict__ cvec, const float* __restrict__ c1vec,
    float* __restrict__ hw, float* __restrict__ rhw,
    const float* __restrict__ xT,
    float* __restrict__ Gz, float* __restrict__ Gh,
    uint32_t* __restrict__ bar, float* __restrict__ out, const int T)
{
  __shared__ float lds[5120];
  float* red = lds;              // [4 waves][16 c][64 lanes]
  float* ttr = lds + 4096;       // [64 b][16 d] out-transpose staging

  const int bid = blockIdx.x, tid = threadIdx.x;
  const int wave = __builtin_amdgcn_readfirstlane(tid >> 6);  // keep wave id scalar
  const int lane = tid & 63;
  const int bh = bid >> 7, chnk = bid & 127;   // phase A: 2 b-halves x 128 col-chunks(16)
  const int typ = chnk >> 5;                   // 0:r 1:z 2:h 3:out
  const int b = bh * 64 + lane;
  const int xcd = bid & 7;
  uint32_t ph = 0;

  for (int s = 1; s <= T; ++s) {
    // ======== phase A : pre = src @ M (+bias), per-type epilogue ========
    {
      const float* hsrc = (s == 1) ? xT : hw;
      const float* Msrc = ((s == 1) ? M1w : Mw) + (chnk * 512 + wave * 128) * 16;
      const float* cv = (s == 1) ? c1vec : cvec;
      float acc[16];
      #pragma unroll
      for (int c = 0; c < 16; ++c) acc[c] = 0.f;
      const float* hp = hsrc + (wave * 128) * 128 + b;
      float hv[16];
      #pragma unroll
      for (int u = 0; u < 16; ++u) hv[u] = hp[u * 128];
      for (int kb = 0; kb < 128; kb += 16) {
        #pragma unroll
        for (int u = 0; u < 16; ++u) {
          const float cur = hv[u];
          hv[u] = hp[(kb + 16 + u) * 128];            // prefetch (lands in pad rows at end)
          const float* mrow = Msrc + (kb + u) * 16;   // wave-uniform weight row
          #pragma unroll
          for (int c = 0; c < 16; ++c) acc[c] = fmaf(cur, mrow[c], acc[c]);
        }
      }
      #pragma unroll
      for (int c = 0; c < 16; ++c) red[(wave * 16 + c) * 64 + lane] = acc[c];
      __syncthreads();
      float vout[4];
      const int cg = tid >> 6, lane_ = tid & 63;
      const int bb = bh * 64 + lane_;
      #pragma unroll
      for (int i = 0; i < 4; ++i) {
        const int c = cg * 4 + i;
        float v = red[c * 64 + lane_] + red[(16 + c) * 64 + lane_]
                + red[(32 + c) * 64 + lane_] + red[(48 + c) * 64 + lane_];
        vout[i] = v + cv[chnk * 16 + c];
      }
      if (typ == 0) {               // r gate -> rh = sigmoid(pre) * h_prev
        #pragma unroll
        for (int i = 0; i < 4; ++i) {
          const int cglob = chnk * 16 + cg * 4 + i;
          rhw[cglob * 128 + bb] = sigm(vout[i]) * hw[cglob * 128 + bb];
        }
      } else if (typ == 1) {        // z gate (store activated)
        #pragma unroll
        for (int i = 0; i < 4; ++i) {
          const int cglob = chnk * 16 + cg * 4 + i;
          Gz[(cglob - 512) * 128 + bb] = sigm(vout[i]);
        }
      } else if (typ == 2) {        // pre-h (x part + bias)
        #pragma unroll
        for (int i = 0; i < 4; ++i) {
          const int cglob = chnk * 16 + cg * 4 + i;
          Gh[(cglob - 1024) * 128 + bb] = vout[i];
        }
      } else if (s > 1) {           // out_{s-1} -> d_out[:, s-1, :] via LDS remap
        __syncthreads();
        #pragma unroll
        for (int i = 0; i < 4; ++i) ttr[lane_ * 16 + cg * 4 + i] = vout[i];
        __syncthreads();
        const int bq = tid >> 2, dq = tid & 3;
        const float4 o4 = *(const float4*)&ttr[bq * 16 + dq * 4];
        const int bglob = bh * 64 + bq;
        const int d0 = (chnk - 96) * 16 + dq * 4;
        *(float4*)&out[(size_t)bglob * (size_t)T * 512 + (size_t)(s - 1) * 512 + d0] = o4;
      }
    }
    gbar(bar, xcd, ph++);

    if (s < T) {
      if (bid < 128) {
        // ======== phase B : S = rh @ Uh ; h update ========
        const int bh2 = bid >> 6, ch2 = bid & 63;
        const int b2 = bh2 * 64 + lane;
        const float* Usrc = Uhw + (ch2 * 512 + wave * 128) * 8;
        float acc[8];
        #pragma unroll
        for (int c = 0; c < 8; ++c) acc[c] = 0.f;
        const float* rp = rhw + (wave * 128) * 128 + b2;
        float hv[16];
        #pragma unroll
        for (int u = 0; u < 16; ++u) hv[u] = rp[u * 128];
        for (int kb = 0; kb < 128; kb += 16) {
          #pragma unroll
          for (int u = 0; u < 16; ++u) {
            const float cur = hv[u];
            hv[u] = rp[(kb + 16 + u) * 128];
            const float* urow = Usrc + (kb + u) * 8;
            #pragma unroll
            for (int c = 0; c < 8; ++c) acc[c] = fmaf(cur, urow[c], acc[c]);
          }
        }
        #pragma unroll
        for (int c = 0; c < 8; ++c) red[(wave * 8 + c) * 64 + lane] = acc[c];
        __syncthreads();
        const int cg = tid >> 6, lane_ = tid & 63;
        const int bb = bh2 * 64 + lane_;
        #pragma unroll
        for (int i = 0; i < 2; ++i) {
          const int ci = cg * 2 + i;
          const float S = red[ci * 64 + lane_] + red[(8 + ci) * 64 + lane_]
                        + red[(16 + ci) * 64 + lane_] + red[(24 + ci) * 64 + lane_];
          const int c = ch2 * 8 + ci;
          const float z = Gz[c * 128 + bb];
          const float gh = Gh[c * 128 + bb] + S;
          const float hprev = hw[c * 128 + bb];
          float hn = (1.f - z) * hprev + z * tanh_fast(gh);
          hn = fminf(5.f, fmaxf(-5.f, hn));
          hw[c * 128 + bb] = hn;
        }
      } else if (s == 1) {
        // out[:, 0, :] = inputs  (done once by otherwise-idle blocks)
        const int j = bid - 128;
        for (int idx = tid; idx < 512; idx += 256)
          out[(size_t)j * (size_t)T * 512 + idx] = inputs[j * 512 + idx];
      }
      gbar(bar, xcd, ph++);
    }
  }
}

// ======================= host launcher =======================
extern "C" void kernel_launch(void* const* d_in, const int* in_sizes, int n_in,
                              void* d_out, int out_size, void* d_ws, size_t ws_size,
                              hipStream_t stream) {
  const float* inputs = (const float*)d_in[0];
  const float* Wz = (const float*)d_in[1];
  const float* Wr = (const float*)d_in[2];
  const float* Wh = (const float*)d_in[3];
  const float* Uz = (const float*)d_in[4];
  const float* Ur = (const float*)d_in[5];
  const float* Uh = (const float*)d_in[6];
  const float* bz = (const float*)d_in[7];
  const float* br = (const float*)d_in[8];
  const float* bh = (const float*)d_in[9];
  const float* Wo = (const float*)d_in[10];
  const float* bo = (const float*)d_in[11];
  float* ws = (float*)d_ws;
  const int T = out_size / (128 * 512);

  gru_pre<<<dim3(320), dim3(256), 0, stream>>>(inputs, Wz, Wr, Wh, Uz, Ur, Uh,
                                               bz, br, bh, Wo, bo, ws);
  gru_main<<<dim3(256), dim3(256), 0, stream>>>(
      inputs, ws + OFF_M, ws + OFF_M1, ws + OFF_UH, ws + OFF_CV, ws + OFF_C1,
      ws + OFF_H, ws + OFF_RH, ws + OFF_XT, ws + OFF_GZ, ws + OFF_GH,
      (uint32_t*)(ws + OFF_BAR), (float*)d_out, T);
}

// Round 2
// 18331.339 us; speedup vs baseline: 1.4883x; 1.4883x over previous
//
#include <hip/hip_runtime.h>
#include <cstdint>

#define NB 128      // batch
#define DH 512      // D == H
#define ROWS 528    // DH + 16 pad rows (prefetch overrun)

// ---- workspace layout (float offsets) ----
#define OFF_M   0u          // [128 chunks][512 k][16 c]  folded [Ar|Az|Ah|Wo]
#define OFF_M1  1048576u    // [128][512][16]             step-1 [Wr|Wz|Wh|0]
#define OFF_UH  2097152u    // [128 chunks][512 k][4 c]   Uh
#define OFF_H   2359296u    // [528][128]  h (transposed, padded)
#define OFF_RH  2426880u    // [528][128]  r*h
#define OFF_XT  2494464u    // [528][128]  inputs^T
#define OFF_GZ  2562048u    // [512][128]  z gate (activated)
#define OFF_GH  2627584u    // [512][128]  pre-h (x-part + bias)
#define OFF_CV  2693120u    // [2048] folded biases
#define OFF_C1  2695168u    // [2048] step-1 biases
#define OFF_BAR 2697216u    // 1024 uint32 barrier state

__device__ __forceinline__ float sigm(float x) { return 1.f / (1.f + __expf(-x)); }
__device__ __forceinline__ float tanh_fast(float x) {
  float e = __expf(2.f * fminf(x, 40.f));
  return (e - 1.f) / (e + 1.f);
}

// ======================= precompute kernel =======================
__global__ __launch_bounds__(256) void gru_pre(
    const float* __restrict__ inputs,
    const float* __restrict__ Wz, const float* __restrict__ Wr, const float* __restrict__ Wh,
    const float* __restrict__ Uz, const float* __restrict__ Ur, const float* __restrict__ Uh,
    const float* __restrict__ bz, const float* __restrict__ br, const float* __restrict__ bh,
    const float* __restrict__ Wo, const float* __restrict__ bo,
    float* __restrict__ ws)
{
  __shared__ float sh[8960];            // 35 KB scratch, reused per task
  const int bid = blockIdx.x, t = threadIdx.x;
  float* Mw  = ws + OFF_M;
  float* M1w = ws + OFF_M1;
  float* Uhw = ws + OFF_UH;
  float* hw  = ws + OFF_H;
  float* rhw = ws + OFF_RH;
  float* xT  = ws + OFF_XT;
  float* cv  = ws + OFF_CV;
  float* c1  = ws + OFF_C1;
  uint32_t* bar = (uint32_t*)(ws + OFF_BAR);

  if (bid < 256) {
    // ---- build M = [Wo@Wr+Ur | Wo@Wz+Uz | Wo@Wh | Wo] ----
    const int kh = bid >> 7, cch = bid & 127;
    const int reg = cch >> 5;
    const int k0 = kh * 256, c0 = cch * 16;
    if (reg == 3) {
      const int cc0 = c0 - 1536;
      for (int i = 0; i < 16; ++i) {
        int idx = t + i * 256;
        int kk = k0 + (idx >> 4), ci = idx & 15;
        Mw[(cch * 512 + kk) * 16 + ci] = Wo[kk * 512 + cc0 + ci];
      }
    } else {
      const float* Ws = (reg == 0) ? Wr : (reg == 1) ? Wz : Wh;
      const float* Us = (reg == 0) ? Ur : (reg == 1) ? Uz : nullptr;
      const int cc0 = c0 - reg * 512;
      const int kl = t;                 // 256 threads <-> 256 local k rows
      const int k = k0 + kl;
      float acc[16];
      #pragma unroll
      for (int c = 0; c < 16; ++c) acc[c] = 0.f;
      for (int jt = 0; jt < 16; ++jt) {          // 32-wide j tiles of Wo
        __syncthreads();
        for (int i = 0; i < 32; ++i) {
          int idx = t + i * 256;                 // 8192 = 256k x 32j
          int kk = idx >> 5, jj = idx & 31;
          sh[kk * 35 + jj] = Wo[(k0 + kk) * 512 + jt * 32 + jj];
        }
        __syncthreads();
        for (int j = 0; j < 32; ++j) {
          float wv = sh[kl * 35 + j];
          const float* wrow = Ws + (jt * 32 + j) * 512 + cc0;
          #pragma unroll
          for (int c = 0; c < 16; ++c) acc[c] = fmaf(wv, wrow[c], acc[c]);
        }
      }
      #pragma unroll
      for (int c = 0; c < 16; ++c) {
        float v = acc[c];
        if (Us) v += Us[k * 512 + cc0 + c];
        Mw[(cch * 512 + k) * 16 + c] = v;
      }
    }
  }
  else if (bid < 264) {
    // ---- cvec = bo @ W* + b*   (region 3: just bo) ----
    const int q = bid - 256;
    const int r2 = q >> 1;
    const float* Ws = (r2 == 0) ? Wr : (r2 == 1) ? Wz : (r2 == 2) ? Wh : nullptr;
    const float* bs = (r2 == 0) ? br : (r2 == 1) ? bz : (r2 == 2) ? bh : nullptr;
    for (int round = 0; round < 8; ++round) {
      int col32 = t >> 3, strip = t & 7;
      int c = q * 256 + round * 32 + col32;
      int cc = c & 511;
      float p = 0.f;
      if (r2 < 3) {
        for (int j = strip * 64; j < strip * 64 + 64; ++j)
          p = fmaf(bo[j], Ws[j * 512 + cc], p);
      }
      sh[col32 * 8 + strip] = p;
      __syncthreads();
      if (t < 32) {
        float v = 0.f;
        #pragma unroll
        for (int st = 0; st < 8; ++st) v += sh[t * 8 + st];
        int c2 = q * 256 + round * 32 + t;
        int cc2 = c2 & 511;
        cv[c2] = (r2 < 3) ? (v + bs[cc2]) : bo[cc2];
      }
      __syncthreads();
    }
  }
  else if (bid < 288) {
    // ---- M1 = [Wr|Wz|Wh] copy (chunks 0..95) ----
    const int q = bid - 264;
    for (int cq = 0; cq < 4; ++cq) {
      int ch = q * 4 + cq;
      int r3 = ch >> 5;
      const float* Ws = (r3 == 0) ? Wr : (r3 == 1) ? Wz : Wh;
      int cc0 = (ch & 31) * 16;
      for (int i = 0; i < 32; ++i) {
        int idx = t + i * 256;
        int kk = idx >> 4, ci = idx & 15;
        M1w[(ch * 512 + kk) * 16 + ci] = Ws[kk * 512 + cc0 + ci];
      }
    }
  }
  else if (bid < 296) {
    // ---- M1 Wo-part zero (chunks 96..127) ----
    const int q = bid - 288;
    for (int cq = 0; cq < 4; ++cq) {
      int ch = 96 + q * 4 + cq;
      for (int i = 0; i < 32; ++i) {
        int idx = t + i * 256;
        M1w[ch * 8192 + idx] = 0.f;
      }
    }
  }
  else if (bid < 312) {
    // ---- Uh reshape to [128 chunks][512 k][4 c] ----
    const int q = bid - 296;
    for (int cq = 0; cq < 8; ++cq) {
      int ch = q * 8 + cq;
      for (int i = 0; i < 8; ++i) {
        int idx = t + i * 256;
        int kk = idx >> 2, ci = idx & 3;
        Uhw[(ch * 512 + kk) * 4 + ci] = Uh[kk * 512 + ch * 4 + ci];
      }
    }
  }
  else if (bid < 316) {
    // ---- xT = inputs^T (64x64 LDS tiles) ----
    const int q = bid - 312;
    for (int ti = q * 4; ti < q * 4 + 4; ++ti) {
      int bt = ti >> 3, dt = ti & 7;
      __syncthreads();
      for (int i = 0; i < 16; ++i) {
        int idx = t + i * 256;
        int r = idx >> 6, c = idx & 63;
        sh[r * 65 + c] = inputs[(bt * 64 + r) * 512 + dt * 64 + c];
      }
      __syncthreads();
      for (int i = 0; i < 16; ++i) {
        int idx = t + i * 256;
        int r = idx >> 6, c = idx & 63;
        xT[(dt * 64 + r) * 128 + bt * 64 + c] = sh[c * 65 + r];
      }
    }
    if (q == 0) {
      for (int idx = t; idx < 16 * 128; idx += 256) xT[512 * 128 + idx] = 0.f;
    }
  }
  else if (bid == 316) {
    for (int idx = t; idx < ROWS * 128; idx += 256) hw[idx] = 0.f;     // h0 = 0 (+pads)
  }
  else if (bid == 317) {
    for (int idx = t; idx < 16 * 128; idx += 256) rhw[512 * 128 + idx] = 0.f;  // rh pads
  }
  else if (bid == 318) {
    for (int idx = t; idx < 2048; idx += 256)
      c1[idx] = (idx < 512) ? br[idx] : (idx < 1024) ? bz[idx - 512]
              : (idx < 1536) ? bh[idx - 1024] : 0.f;
    for (int idx = t; idx < 1024; idx += 256) bar[idx] = 0u;
  }
}

// ======================= global barrier =======================
__device__ __forceinline__ void gbar(uint32_t* bar, int xcd, uint32_t ph) {
  __syncthreads();
  if (threadIdx.x == 0) {
    __threadfence();  // release our writes to device scope
    uint32_t o = __hip_atomic_fetch_add(&bar[xcd * 32], 1u, __ATOMIC_RELAXED, __HIP_MEMORY_SCOPE_AGENT);
    if (o == ph * 32u + 31u) {                    // last of this xcd-group
      uint32_t g = __hip_atomic_fetch_add(&bar[256], 1u, __ATOMIC_RELAXED, __HIP_MEMORY_SCOPE_AGENT);
      if (g == ph * 8u + 7u) {                    // last globally
        #pragma unroll
        for (int x = 0; x < 8; ++x)
          __hip_atomic_store(&bar[512 + x * 32], ph + 1u, __ATOMIC_RELAXED, __HIP_MEMORY_SCOPE_AGENT);
      }
    }
    int guard = 0;
    while (__hip_atomic_load(&bar[512 + xcd * 32], __ATOMIC_RELAXED, __HIP_MEMORY_SCOPE_AGENT) < ph + 1u) {
      __builtin_amdgcn_s_sleep(1);
      if (++guard > (1 << 24)) break;             // anti-hang safety
    }
    __threadfence();  // acquire: invalidate caches before reading others' data
  }
  __syncthreads();
}

// ======================= persistent main kernel =======================
// 256 blocks x 512 threads (8 waves, 2/SIMD). Weights live in LDS.
// Phase A: block = (bh in 0..1) x (chnk in 0..127, 16 cols); K=512 split 8 waves x 64.
// Phase B: block = (bh) x (chnk -> 4 cols); K=512 split 8 waves x 64.
__global__ __launch_bounds__(512, 2) void gru_main(
    const float* __restrict__ inputs,
    const float* __restrict__ Mw, const float* __restrict__ M1w,
    const float* __restrict__ Uhw,
    const float* __restrict__ cvec, const float* __restrict__ c1vec,
    float* __restrict__ hw, float* __restrict__ rhw,
    const float* __restrict__ xT,
    float* __restrict__ Gz, float* __restrict__ Gh,
    uint32_t* __restrict__ bar, float* __restrict__ out, const int T)
{
  __shared__ float Ald[8192];   // 32 KB  block's A-weight slice [512 k][16 c]
  __shared__ float Uld[2048];   //  8 KB  block's B-weight slice [512 k][4 c]
  __shared__ float red[4096];   // 16 KB  [4 slots][16 c][64 lanes]
  __shared__ float ttr[1024];   //  4 KB  [64 b][16 d] out-transpose staging

  const int bid = blockIdx.x, tid = threadIdx.x;
  const int wave = __builtin_amdgcn_readfirstlane(tid >> 6);  // 0..7, scalar
  const int lane = tid & 63;
  const int bh = bid >> 7, chnk = bid & 127;
  const int typ = chnk >> 5;                   // 0:r 1:z 2:h 3:out
  const int b = bh * 64 + lane;
  const int xcd = bid & 7;
  uint32_t ph = 0;

  // ---- initial stage: M1 slice + Uh slice into LDS ----
  {
    const float* src = M1w + chnk * 8192;
    #pragma unroll
    for (int i = 0; i < 4; ++i) {
      const int idx4 = tid + i * 512;
      *(float4*)&Ald[idx4 * 4] = *(const float4*)&src[idx4 * 4];
    }
    *(float4*)&Uld[tid * 4] = *(const float4*)&Uhw[chnk * 2048 + tid * 4];
  }
  __syncthreads();

  for (int s = 1; s <= T; ++s) {
    // ======== phase A : pre = src @ M (+bias), per-type epilogue ========
    {
      const float* hsrc = (s == 1) ? xT : hw;
      const float* cv = (s == 1) ? c1vec : cvec;
      float acc[16];
      #pragma unroll
      for (int c = 0; c < 16; ++c) acc[c] = 0.f;
      const float* hp = hsrc + (wave * 64) * 128 + b;
      float hv[16];
      #pragma unroll
      for (int u = 0; u < 16; ++u) hv[u] = hp[u * 128];
      for (int kb = 0; kb < 64; kb += 16) {
        #pragma unroll
        for (int u = 0; u < 16; ++u) {
          const float cur = hv[u];
          hv[u] = hp[(kb + 16 + u) * 128];          // prefetch (pads absorb overrun)
          const float* mrow = &Ald[(wave * 64 + kb + u) * 16];  // uniform LDS row
          #pragma unroll
          for (int c = 0; c < 16; ++c) acc[c] = fmaf(cur, mrow[c], acc[c]);
        }
      }
      // two-stage cross-wave reduction (8 -> 4 -> epilogue)
      if (wave >= 4) {
        #pragma unroll
        for (int c = 0; c < 16; ++c) red[((wave - 4) * 16 + c) * 64 + lane] = acc[c];
      }
      __syncthreads();
      if (wave < 4) {
        #pragma unroll
        for (int c = 0; c < 16; ++c) red[(wave * 16 + c) * 64 + lane] += acc[c];
      }
      __syncthreads();
      const int cg = tid >> 6, lane_ = tid & 63;
      const int bb = bh * 64 + lane_;
      float vout[2];
      #pragma unroll
      for (int i = 0; i < 2; ++i) {
        const int c = cg * 2 + i;
        float v = red[c * 64 + lane_] + red[(16 + c) * 64 + lane_]
                + red[(32 + c) * 64 + lane_] + red[(48 + c) * 64 + lane_];
        vout[i] = v + cv[chnk * 16 + c];
      }
      if (typ == 0) {               // r gate -> rh = sigmoid(pre) * h_prev
        #pragma unroll
        for (int i = 0; i < 2; ++i) {
          const int cglob = chnk * 16 + cg * 2 + i;
          rhw[cglob * 128 + bb] = sigm(vout[i]) * hw[cglob * 128 + bb];
        }
      } else if (typ == 1) {        // z gate (store activated)
        #pragma unroll
        for (int i = 0; i < 2; ++i) {
          const int cglob = chnk * 16 + cg * 2 + i;
          Gz[(cglob - 512) * 128 + bb] = sigm(vout[i]);
        }
      } else if (typ == 2) {        // pre-h (x part + bias)
        #pragma unroll
        for (int i = 0; i < 2; ++i) {
          const int cglob = chnk * 16 + cg * 2 + i;
          Gh[(cglob - 1024) * 128 + bb] = vout[i];
        }
      } else if (s > 1) {           // out_{s-1} -> d_out[:, s-1, :] via LDS remap
        #pragma unroll
        for (int i = 0; i < 2; ++i) ttr[lane_ * 16 + cg * 2 + i] = vout[i];
        __syncthreads();
        const int bq = tid >> 3, pr = tid & 7;
        const float2 o2 = *(const float2*)&ttr[bq * 16 + pr * 2];
        const int bglob = bh * 64 + bq;
        const int d0 = (chnk - 96) * 16 + pr * 2;
        *(float2*)&out[(size_t)bglob * (size_t)T * 512 + (size_t)(s - 1) * 512 + d0] = o2;
      }
    }
    gbar(bar, xcd, ph++);

    if (s < T) {
      if (s == 1) {
        // restage Ald with the folded M (used from s==2 on)
        const float* src = Mw + chnk * 8192;
        #pragma unroll
        for (int i = 0; i < 4; ++i) {
          const int idx4 = tid + i * 512;
          *(float4*)&Ald[idx4 * 4] = *(const float4*)&src[idx4 * 4];
        }
        // out[:, 0, :] = inputs (256 floats per block)
        if (tid < 256) {
          const int g = bid * 256 + tid;
          out[(size_t)(g >> 9) * (size_t)T * 512 + (g & 511)] = inputs[g];
        }
      }
      // ======== phase B : S = rh @ Uh ; h update ========
      {
        float acc[4];
        #pragma unroll
        for (int c = 0; c < 4; ++c) acc[c] = 0.f;
        const float* rp = rhw + (wave * 64) * 128 + b;
        float hv[16];
        #pragma unroll
        for (int u = 0; u < 16; ++u) hv[u] = rp[u * 128];
        for (int kb = 0; kb < 64; kb += 16) {
          #pragma unroll
          for (int u = 0; u < 16; ++u) {
            const float cur = hv[u];
            hv[u] = rp[(kb + 16 + u) * 128];
            const float* urow = &Uld[(wave * 64 + kb + u) * 4];
            #pragma unroll
            for (int c = 0; c < 4; ++c) acc[c] = fmaf(cur, urow[c], acc[c]);
          }
        }
        if (wave >= 4) {
          #pragma unroll
          for (int c = 0; c < 4; ++c) red[((wave - 4) * 4 + c) * 64 + lane] = acc[c];
        }
        __syncthreads();
        if (wave < 4) {
          #pragma unroll
          for (int c = 0; c < 4; ++c) red[(wave * 4 + c) * 64 + lane] += acc[c];
        }
        __syncthreads();
        const int cg = tid >> 6, lane_ = tid & 63;
        if (cg < 4) {
          const float S = red[(cg) * 64 + lane_] + red[(4 + cg) * 64 + lane_]
                        + red[(8 + cg) * 64 + lane_] + red[(12 + cg) * 64 + lane_];
          const int c = chnk * 4 + cg;
          const int bb = bh * 64 + lane_;
          const float z = Gz[c * 128 + bb];
          const float gh = Gh[c * 128 + bb] + S;
          const float hprev = hw[c * 128 + bb];
          float hn = (1.f - z) * hprev + z * tanh_fast(gh);
          hn = fminf(5.f, fmaxf(-5.f, hn));
          hw[c * 128 + bb] = hn;
        }
      }
      gbar(bar, xcd, ph++);
    }
  }
}

// ======================= host launcher =======================
extern "C" void kernel_launch(void* const* d_in, const int* in_sizes, int n_in,
                              void* d_out, int out_size, void* d_ws, size_t ws_size,
                              hipStream_t stream) {
  const float* inputs = (const float*)d_in[0];
  const float* Wz = (const float*)d_in[1];
  const float* Wr = (const float*)d_in[2];
  const float* Wh = (const float*)d_in[3];
  const float* Uz = (const float*)d_in[4];
  const float* Ur = (const float*)d_in[5];
  const float* Uh = (const float*)d_in[6];
  const float* bz = (const float*)d_in[7];
  const float* br = (const float*)d_in[8];
  const float* bh = (const float*)d_in[9];
  const float* Wo = (const float*)d_in[10];
  const float* bo = (const float*)d_in[11];
  float* ws = (float*)d_ws;
  const int T = out_size / (128 * 512);

  gru_pre<<<dim3(320), dim3(256), 0, stream>>>(inputs, Wz, Wr, Wh, Uz, Ur, Uh,
                                               bz, br, bh, Wo, bo, ws);
  gru_main<<<dim3(256), dim3(512), 0, stream>>>(
      inputs, ws + OFF_M, ws + OFF_M1, ws + OFF_UH, ws + OFF_CV, ws + OFF_C1,
      ws + OFF_H, ws + OFF_RH, ws + OFF_XT, ws + OFF_GZ, ws + OFF_GH,
      (uint32_t*)(ws + OFF_BAR), (float*)d_out, T);
}

// Round 3
// 7070.712 us; speedup vs baseline: 3.8586x; 2.5926x over previous
//
#include <hip/hip_runtime.h>
#include <cstdint>

#define NB 128      // batch
#define DH 512      // D == H
#define ROWS 528    // DH + 16 pad rows (kept, though peeled loops no longer overrun)

// ---- workspace layout (float offsets) ----
#define OFF_M   0u          // [128 chunks][512 k][16 c]  folded [Ar|Az|Ah|Wo]
#define OFF_M1  1048576u    // [128][512][16]             step-1 [Wr|Wz|Wh|0]
#define OFF_UH  2097152u    // [64 chunks][512 k][8 c]    Uh
#define OFF_H   2359296u    // [528][128]  h (transposed, padded)
#define OFF_RH  2426880u    // [528][128]  r*h
#define OFF_XT  2494464u    // [528][128]  inputs^T
#define OFF_GZ  2562048u    // [512][128]  z gate (activated)
#define OFF_GH  2627584u    // [512][128]  pre-h (x-part + bias)
#define OFF_CV  2693120u    // [2048] folded biases
#define OFF_C1  2695168u    // [2048] step-1 biases
#define OFF_BAR 2697216u    // 1024 uint32 barrier state

__device__ __forceinline__ float sigm(float x) { return 1.f / (1.f + __expf(-x)); }
__device__ __forceinline__ float tanh_fast(float x) {
  float e = __expf(2.f * fminf(x, 40.f));
  return (e - 1.f) / (e + 1.f);
}

// Coherent (agent-scope, L2-bypassing) access: compiles to global_load/store sc0 sc1.
// No fences needed anywhere — these always hit the coherence point (L3).
__device__ __forceinline__ float cload(const float* p) {
  return __hip_atomic_load(p, __ATOMIC_RELAXED, __HIP_MEMORY_SCOPE_AGENT);
}
__device__ __forceinline__ void cstore(float* p, float v) {
  __hip_atomic_store(p, v, __ATOMIC_RELAXED, __HIP_MEMORY_SCOPE_AGENT);
}

// ======================= precompute kernel =======================
__global__ __launch_bounds__(256) void gru_pre(
    const float* __restrict__ inputs,
    const float* __restrict__ Wz, const float* __restrict__ Wr, const float* __restrict__ Wh,
    const float* __restrict__ Uz, const float* __restrict__ Ur, const float* __restrict__ Uh,
    const float* __restrict__ bz, const float* __restrict__ br, const float* __restrict__ bh,
    const float* __restrict__ Wo, const float* __restrict__ bo,
    float* __restrict__ ws)
{
  __shared__ float sh[8960];            // 35 KB scratch, reused per task
  const int bid = blockIdx.x, t = threadIdx.x;
  float* Mw  = ws + OFF_M;
  float* M1w = ws + OFF_M1;
  float* Uhw = ws + OFF_UH;
  float* hw  = ws + OFF_H;
  float* rhw = ws + OFF_RH;
  float* xT  = ws + OFF_XT;
  float* cv  = ws + OFF_CV;
  float* c1  = ws + OFF_C1;
  uint32_t* bar = (uint32_t*)(ws + OFF_BAR);

  if (bid < 256) {
    // ---- build M = [Wo@Wr+Ur | Wo@Wz+Uz | Wo@Wh | Wo] ----
    const int kh = bid >> 7, cch = bid & 127;
    const int reg = cch >> 5;
    const int k0 = kh * 256, c0 = cch * 16;
    if (reg == 3) {
      const int cc0 = c0 - 1536;
      for (int i = 0; i < 16; ++i) {
        int idx = t + i * 256;
        int kk = k0 + (idx >> 4), ci = idx & 15;
        Mw[(cch * 512 + kk) * 16 + ci] = Wo[kk * 512 + cc0 + ci];
      }
    } else {
      const float* Ws = (reg == 0) ? Wr : (reg == 1) ? Wz : Wh;
      const float* Us = (reg == 0) ? Ur : (reg == 1) ? Uz : nullptr;
      const int cc0 = c0 - reg * 512;
      const int kl = t;                 // 256 threads <-> 256 local k rows
      const int k = k0 + kl;
      float acc[16];
      #pragma unroll
      for (int c = 0; c < 16; ++c) acc[c] = 0.f;
      for (int jt = 0; jt < 16; ++jt) {          // 32-wide j tiles of Wo
        __syncthreads();
        for (int i = 0; i < 32; ++i) {
          int idx = t + i * 256;                 // 8192 = 256k x 32j
          int kk = idx >> 5, jj = idx & 31;
          sh[kk * 35 + jj] = Wo[(k0 + kk) * 512 + jt * 32 + jj];
        }
        __syncthreads();
        for (int j = 0; j < 32; ++j) {
          float wv = sh[kl * 35 + j];
          const float* wrow = Ws + (jt * 32 + j) * 512 + cc0;
          #pragma unroll
          for (int c = 0; c < 16; ++c) acc[c] = fmaf(wv, wrow[c], acc[c]);
        }
      }
      #pragma unroll
      for (int c = 0; c < 16; ++c) {
        float v = acc[c];
        if (Us) v += Us[k * 512 + cc0 + c];
        Mw[(cch * 512 + k) * 16 + c] = v;
      }
    }
  }
  else if (bid < 264) {
    // ---- cvec = bo @ W* + b*   (region 3: just bo) ----
    const int q = bid - 256;
    const int r2 = q >> 1;
    const float* Ws = (r2 == 0) ? Wr : (r2 == 1) ? Wz : (r2 == 2) ? Wh : nullptr;
    const float* bs = (r2 == 0) ? br : (r2 == 1) ? bz : (r2 == 2) ? bh : nullptr;
    for (int round = 0; round < 8; ++round) {
      int col32 = t >> 3, strip = t & 7;
      int c = q * 256 + round * 32 + col32;
      int cc = c & 511;
      float p = 0.f;
      if (r2 < 3) {
        for (int j = strip * 64; j < strip * 64 + 64; ++j)
          p = fmaf(bo[j], Ws[j * 512 + cc], p);
      }
      sh[col32 * 8 + strip] = p;
      __syncthreads();
      if (t < 32) {
        float v = 0.f;
        #pragma unroll
        for (int st = 0; st < 8; ++st) v += sh[t * 8 + st];
        int c2 = q * 256 + round * 32 + t;
        int cc2 = c2 & 511;
        cv[c2] = (r2 < 3) ? (v + bs[cc2]) : bo[cc2];
      }
      __syncthreads();
    }
  }
  else if (bid < 288) {
    // ---- M1 = [Wr|Wz|Wh] copy (chunks 0..95) ----
    const int q = bid - 264;
    for (int cq = 0; cq < 4; ++cq) {
      int ch = q * 4 + cq;
      int r3 = ch >> 5;
      const float* Ws = (r3 == 0) ? Wr : (r3 == 1) ? Wz : Wh;
      int cc0 = (ch & 31) * 16;
      for (int i = 0; i < 32; ++i) {
        int idx = t + i * 256;
        int kk = idx >> 4, ci = idx & 15;
        M1w[(ch * 512 + kk) * 16 + ci] = Ws[kk * 512 + cc0 + ci];
      }
    }
  }
  else if (bid < 296) {
    // ---- M1 Wo-part zero (chunks 96..127) ----
    const int q = bid - 288;
    for (int cq = 0; cq < 4; ++cq) {
      int ch = 96 + q * 4 + cq;
      for (int i = 0; i < 32; ++i) {
        int idx = t + i * 256;
        M1w[ch * 8192 + idx] = 0.f;
      }
    }
  }
  else if (bid < 312) {
    // ---- Uh reshape to [64 chunks][512 k][8 c] ----
    const int q = bid - 296;
    for (int cq = 0; cq < 4; ++cq) {
      int ch = q * 4 + cq;
      for (int i = 0; i < 16; ++i) {
        int idx = t + i * 256;
        int kk = idx >> 3, ci = idx & 7;
        Uhw[(ch * 512 + kk) * 8 + ci] = Uh[kk * 512 + ch * 8 + ci];
      }
    }
  }
  else if (bid < 316) {
    // ---- xT = inputs^T (64x64 LDS tiles) ----
    const int q = bid - 312;
    for (int ti = q * 4; ti < q * 4 + 4; ++ti) {
      int bt = ti >> 3, dt = ti & 7;
      __syncthreads();
      for (int i = 0; i < 16; ++i) {
        int idx = t + i * 256;
        int r = idx >> 6, c = idx & 63;
        sh[r * 65 + c] = inputs[(bt * 64 + r) * 512 + dt * 64 + c];
      }
      __syncthreads();
      for (int i = 0; i < 16; ++i) {
        int idx = t + i * 256;
        int r = idx >> 6, c = idx & 63;
        xT[(dt * 64 + r) * 128 + bt * 64 + c] = sh[c * 65 + r];
      }
    }
    if (q == 0) {
      for (int idx = t; idx < 16 * 128; idx += 256) xT[512 * 128 + idx] = 0.f;
    }
  }
  else if (bid == 316) {
    for (int idx = t; idx < ROWS * 128; idx += 256) hw[idx] = 0.f;     // h0 = 0 (+pads)
  }
  else if (bid == 317) {
    for (int idx = t; idx < 16 * 128; idx += 256) rhw[512 * 128 + idx] = 0.f;  // rh pads
  }
  else if (bid == 318) {
    for (int idx = t; idx < 2048; idx += 256)
      c1[idx] = (idx < 512) ? br[idx] : (idx < 1024) ? bz[idx - 512]
              : (idx < 1536) ? bh[idx - 1024] : 0.f;
    for (int idx = t; idx < 1024; idx += 256) bar[idx] = 0u;
  }
}

// ======================= global barrier (fence-free) =======================
// Release: __syncthreads() drains every wave's vmcnt (coherent stores reached L3).
// Acquire: readers use sc1 loads which always fetch from the coherence point.
__device__ __forceinline__ void gbar(uint32_t* bar, int xcd, uint32_t ph) {
  __syncthreads();
  if (threadIdx.x == 0) {
    uint32_t o = __hip_atomic_fetch_add(&bar[xcd * 32], 1u, __ATOMIC_RELAXED, __HIP_MEMORY_SCOPE_AGENT);
    if (o == ph * 32u + 31u) {                    // last of this xcd-group
      uint32_t g = __hip_atomic_fetch_add(&bar[256], 1u, __ATOMIC_RELAXED, __HIP_MEMORY_SCOPE_AGENT);
      if (g == ph * 8u + 7u) {                    // last globally
        #pragma unroll
        for (int x = 0; x < 8; ++x)
          __hip_atomic_store(&bar[512 + x * 32], ph + 1u, __ATOMIC_RELAXED, __HIP_MEMORY_SCOPE_AGENT);
      }
    }
    int guard = 0;
    while (__hip_atomic_load(&bar[512 + xcd * 32], __ATOMIC_RELAXED, __HIP_MEMORY_SCOPE_AGENT) < ph + 1u) {
      __builtin_amdgcn_s_sleep(1);
      if (++guard > (1 << 22)) break;             // anti-hang safety
    }
  }
  __syncthreads();
}

// ======================= persistent main kernel =======================
// 256 blocks x 512 threads (8 waves). Weights in LDS; cross-block state via sc1.
// Phase A: 256 blocks = (bh 0..1) x (chnk 0..127 -> 16 cols); K=512 split 8 waves x 64.
// Phase B: 128 blocks = (bh 0..1) x (ch8 0..63 -> 8 cols);   K=512 split 8 waves x 64.
__global__ __launch_bounds__(512, 2) void gru_main(
    const float* __restrict__ inputs,
    const float* __restrict__ Mw, const float* __restrict__ M1w,
    const float* __restrict__ Uhw,
    const float* __restrict__ cvec, const float* __restrict__ c1vec,
    float* __restrict__ hw, float* __restrict__ rhw,
    const float* __restrict__ xT,
    float* __restrict__ Gz, float* __restrict__ Gh,
    uint32_t* __restrict__ bar, float* __restrict__ out, const int T)
{
  __shared__ float Ald[8192];   // 32 KB  block's A-weight slice [512 k][16 c]
  __shared__ float Uld[4096];   // 16 KB  block's B-weight slice [512 k][8 c]
  __shared__ float red[4096];   // 16 KB  cross-wave reduction
  __shared__ float ttr[1024];   //  4 KB  [64 b][16 d] out-transpose staging

  const int bid = blockIdx.x, tid = threadIdx.x;
  const int wave = __builtin_amdgcn_readfirstlane(tid >> 6);  // 0..7, scalar
  const int lane = tid & 63;
  const int bh = bid >> 7, chnk = bid & 127;
  const int typ = chnk >> 5;                   // 0:r 1:z 2:h 3:out
  const int b = bh * 64 + lane;
  const int xcd = bid & 7;
  uint32_t ph = 0;

  // ---- initial stage: M1 slice (all blocks) + Uh slice (blocks <128) ----
  {
    const float* src = M1w + chnk * 8192;
    #pragma unroll
    for (int i = 0; i < 4; ++i) {
      const int idx4 = tid + i * 512;
      *(float4*)&Ald[idx4 * 4] = *(const float4*)&src[idx4 * 4];
    }
    if (bid < 128) {
      const float* us = Uhw + (size_t)(bid & 63) * 4096;
      *(float4*)&Uld[tid * 4]        = ((const float4*)us)[tid];
      *(float4*)&Uld[2048 + tid * 4] = ((const float4*)us)[512 + tid];
    }
  }
  __syncthreads();

  for (int s = 1; s <= T; ++s) {
    // ======== phase A : pre = src @ M (+bias), per-type epilogue ========
    {
      const float* hsrc = (s == 1) ? xT : hw;
      const float* cv = (s == 1) ? c1vec : cvec;
      float acc[16];
      #pragma unroll
      for (int c = 0; c < 16; ++c) acc[c] = 0.f;
      const float* hp = hsrc + (wave * 64) * 128 + b;
      float hv[32];
      #pragma unroll
      for (int u = 0; u < 32; ++u) hv[u] = cload(hp + u * 128);
      #pragma unroll
      for (int u = 0; u < 32; ++u) {              // consume 0..31, prefetch 32..63
        const float cur = hv[u];
        hv[u] = cload(hp + (32 + u) * 128);
        const float* mrow = &Ald[(wave * 64 + u) * 16];
        #pragma unroll
        for (int c = 0; c < 16; ++c) acc[c] = fmaf(cur, mrow[c], acc[c]);
      }
      #pragma unroll
      for (int u = 0; u < 32; ++u) {              // peeled tail: consume 32..63
        const float* mrow = &Ald[(wave * 64 + 32 + u) * 16];
        #pragma unroll
        for (int c = 0; c < 16; ++c) acc[c] = fmaf(hv[u], mrow[c], acc[c]);
      }
      // two-stage cross-wave reduction (8 -> 4 -> epilogue)
      if (wave >= 4) {
        #pragma unroll
        for (int c = 0; c < 16; ++c) red[((wave - 4) * 16 + c) * 64 + lane] = acc[c];
      }
      __syncthreads();
      if (wave < 4) {
        #pragma unroll
        for (int c = 0; c < 16; ++c) red[(wave * 16 + c) * 64 + lane] += acc[c];
      }
      __syncthreads();
      const int cg = tid >> 6, lane_ = tid & 63;
      const int bb = bh * 64 + lane_;
      float vout[2];
      #pragma unroll
      for (int i = 0; i < 2; ++i) {
        const int c = cg * 2 + i;
        float v = red[c * 64 + lane_] + red[(16 + c) * 64 + lane_]
                + red[(32 + c) * 64 + lane_] + red[(48 + c) * 64 + lane_];
        vout[i] = v + cv[chnk * 16 + c];
      }
      if (typ == 0) {               // r gate -> rh = sigmoid(pre) * h_prev
        #pragma unroll
        for (int i = 0; i < 2; ++i) {
          const int cglob = chnk * 16 + cg * 2 + i;
          cstore(&rhw[cglob * 128 + bb], sigm(vout[i]) * cload(&hw[cglob * 128 + bb]));
        }
      } else if (typ == 1) {        // z gate (store activated)
        #pragma unroll
        for (int i = 0; i < 2; ++i) {
          const int cglob = chnk * 16 + cg * 2 + i;
          cstore(&Gz[(cglob - 512) * 128 + bb], sigm(vout[i]));
        }
      } else if (typ == 2) {        // pre-h (x part + bias)
        #pragma unroll
        for (int i = 0; i < 2; ++i) {
          const int cglob = chnk * 16 + cg * 2 + i;
          cstore(&Gh[(cglob - 1024) * 128 + bb], vout[i]);
        }
      } else if (s > 1) {           // out_{s-1} -> d_out[:, s-1, :] via LDS remap
        #pragma unroll
        for (int i = 0; i < 2; ++i) ttr[lane_ * 16 + cg * 2 + i] = vout[i];
        __syncthreads();
        const int bq = tid >> 3, pr = tid & 7;
        const float2 o2 = *(const float2*)&ttr[bq * 16 + pr * 2];
        const int bglob = bh * 64 + bq;
        const int d0 = (chnk - 96) * 16 + pr * 2;
        *(float2*)&out[(size_t)bglob * (size_t)T * 512 + (size_t)(s - 1) * 512 + d0] = o2;
      }
    }
    gbar(bar, xcd, ph++);

    if (s < T) {
      if (s == 1) {
        // restage Ald with the folded M (used from s==2 on)
        const float* src = Mw + chnk * 8192;
        #pragma unroll
        for (int i = 0; i < 4; ++i) {
          const int idx4 = tid + i * 512;
          *(float4*)&Ald[idx4 * 4] = *(const float4*)&src[idx4 * 4];
        }
        // out[:, 0, :] = inputs (idle-in-B blocks do the copy)
        if (bid >= 128) {
          const int j = bid - 128;
          for (int idx = tid; idx < 512; idx += 512)
            ;  // (single pass below)
          if (tid < 512)
            out[(size_t)j * (size_t)T * 512 + tid] = inputs[j * 512 + tid];
        }
      }
      // ======== phase B : S = rh @ Uh ; h update (blocks < 128) ========
      if (bid < 128) {
        const int bh2 = bid >> 6, ch8 = bid & 63;
        const int b2 = bh2 * 64 + lane;
        float acc2[8];
        #pragma unroll
        for (int c = 0; c < 8; ++c) acc2[c] = 0.f;
        const float* rp = rhw + (wave * 64) * 128 + b2;
        float hv[32];
        #pragma unroll
        for (int u = 0; u < 32; ++u) hv[u] = cload(rp + u * 128);
        #pragma unroll
        for (int u = 0; u < 32; ++u) {
          const float cur = hv[u];
          hv[u] = cload(rp + (32 + u) * 128);
          const float* urow = &Uld[(wave * 64 + u) * 8];
          #pragma unroll
          for (int c = 0; c < 8; ++c) acc2[c] = fmaf(cur, urow[c], acc2[c]);
        }
        #pragma unroll
        for (int u = 0; u < 32; ++u) {
          const float* urow = &Uld[(wave * 64 + 32 + u) * 8];
          #pragma unroll
          for (int c = 0; c < 8; ++c) acc2[c] = fmaf(hv[u], urow[c], acc2[c]);
        }
        if (wave >= 4) {
          #pragma unroll
          for (int c = 0; c < 8; ++c) red[((wave - 4) * 8 + c) * 64 + lane] = acc2[c];
        }
        __syncthreads();
        if (wave < 4) {
          #pragma unroll
          for (int c = 0; c < 8; ++c) red[(wave * 8 + c) * 64 + lane] += acc2[c];
        }
        __syncthreads();
        const int cg = tid >> 6, lane_ = tid & 63;
        const float S = red[cg * 64 + lane_] + red[(8 + cg) * 64 + lane_]
                      + red[(16 + cg) * 64 + lane_] + red[(24 + cg) * 64 + lane_];
        const int c = ch8 * 8 + cg;
        const int bb = bh2 * 64 + lane_;
        const float z = cload(&Gz[c * 128 + bb]);
        const float gh = cload(&Gh[c * 128 + bb]) + S;
        const float hprev = cload(&hw[c * 128 + bb]);
        float hn = (1.f - z) * hprev + z * tanh_fast(gh);
        hn = fminf(5.f, fmaxf(-5.f, hn));
        cstore(&hw[c * 128 + bb], hn);
      }
      gbar(bar, xcd, ph++);
    }
  }
}

// ======================= host launcher =======================
extern "C" void kernel_launch(void* const* d_in, const int* in_sizes, int n_in,
                              void* d_out, int out_size, void* d_ws, size_t ws_size,
                              hipStream_t stream) {
  const float* inputs = (const float*)d_in[0];
  const float* Wz = (const float*)d_in[1];
  const float* Wr = (const float*)d_in[2];
  const float* Wh = (const float*)d_in[3];
  const float* Uz = (const float*)d_in[4];
  const float* Ur = (const float*)d_in[5];
  const float* Uh = (const float*)d_in[6];
  const float* bz = (const float*)d_in[7];
  const float* br = (const float*)d_in[8];
  const float* bh = (const float*)d_in[9];
  const float* Wo = (const float*)d_in[10];
  const float* bo = (const float*)d_in[11];
  float* ws = (float*)d_ws;
  const int T = out_size / (128 * 512);

  gru_pre<<<dim3(320), dim3(256), 0, stream>>>(inputs, Wz, Wr, Wh, Uz, Ur, Uh,
                                               bz, br, bh, Wo, bo, ws);
  gru_main<<<dim3(256), dim3(512), 0, stream>>>(
      inputs, ws + OFF_M, ws + OFF_M1, ws + OFF_UH, ws + OFF_CV, ws + OFF_C1,
      ws + OFF_H, ws + OFF_RH, ws + OFF_XT, ws + OFF_GZ, ws + OFF_GH,
      (uint32_t*)(ws + OFF_BAR), (float*)d_out, T);
}